// Round 7
// baseline (444.090 us; speedup 1.0000x reference)
//
#include <hip/hip_runtime.h>
#include <hip/hip_bf16.h>

#define T_LEN 4096
#define NWIN 31
#define EPS_BN 1e-5f

typedef __attribute__((ext_vector_type(8))) short short8;
typedef __attribute__((ext_vector_type(4))) float f32x4;
typedef __attribute__((ext_vector_type(16))) float f32x16;

__device__ __forceinline__ ushort f2bf(float x) {   // round-to-nearest-even bf16
  unsigned u = __float_as_uint(x);
  return (ushort)((u + 0x7FFFu + ((u >> 16) & 1u)) >> 16);
}
__device__ __forceinline__ float bf2f(ushort h) {
  return __uint_as_float((unsigned)h << 16);
}

// ---------------------------------------------------------------- k0: ALL init
// [0,896) conv-bank frags (32x32x16 layout) | [896,960) 1x1 frags | [960,1088) DFT |
// 1088 pool coefs | [1089,1729) wp1 | [1729,1857) wp2 | [1857,2369) w_fu | [2369,2625) w_out
__global__ void k0_all(const float* __restrict__ wt3, const float* __restrict__ wt7,
                       const float* __restrict__ wt15, const float* __restrict__ wt31,
                       const float* __restrict__ w_sp,
                       const float* __restrict__ wp1, const float* __restrict__ wp2,
                       const float* __restrict__ w_fu, const float* __restrict__ w_out,
                       ushort* __restrict__ wfrag, ushort* __restrict__ wfB,
                       ushort* __restrict__ tabf, float4* __restrict__ jc,
                       ushort* __restrict__ wp1f, ushort* __restrict__ wp2f,
                       ushort* __restrict__ wfuf, ushort* __restrict__ woutf) {
  int bid = blockIdx.x;
  int tid = threadIdx.x;
  if (bid < 896) {
    // 32x32x16 A-frag: per (j,ks,h): row = l&31 (och within h-half),
    // k = (l>>5)*8 + i  ->  c = ks*16 + (l>>5)*8 + i
    int e = bid * 256 + tid;
    const float* w; int K, base, eb;
    if (e < 12288)       { w = wt3;  K = 3;  base = 0;   eb = e; }
    else if (e < 40960)  { w = wt7;  K = 7;  base = 48;  eb = e - 12288; }
    else if (e < 102400) { w = wt15; K = 15; base = 160; eb = e - 40960; }
    else                 { w = wt31; K = 31; base = 400; eb = e - 102400; }
    int j = eb / 4096;  int v = eb - j * 4096;
    int ks = v >> 10;   int v2 = v & 1023;
    int h = v2 >> 9;    int wdx = v2 & 511;
    int l = wdx >> 3, i = wdx & 7;
    int o = h * 32 + (l & 31);
    int c = ks * 16 + (l >> 5) * 8 + i;
    float f = w[(o * 64 + c) * K + j];
    ushort hi = f2bf(f);
    ushort lo = f2bf(f - bf2f(hi));
    int fragp = base + ((j * 4 + ks) * 2 + h) * 2;
    wfrag[fragp * 512 + wdx] = hi;
    wfrag[(fragp + 1) * 512 + wdx] = lo;
  } else if (bid < 960) {
    int e = (bid - 896) * 256 + tid;
    int frag = e >> 9;
    int wdx = e & 511;
    int l = wdx >> 3, i = wdx & 7;
    int s = frag >> 2, n = frag & 3;
    int c = s * 32 + 8 * (l >> 4) + i;
    int o = n * 16 + (l & 15);
    float f = w_sp[o * 256 + c];
    ushort hi = f2bf(f);
    ushort lo = f2bf(f - bf2f(hi));
    wfB[(frag * 2 + 0) * 512 + wdx] = hi;
    wfB[(frag * 2 + 1) * 512 + wdx] = lo;
  } else if (bid < 1088) {
    int e = (bid - 960) * 256 + tid;
    int fp = e >> 9;
    int wdx = e & 511;
    int l = wdx >> 3, i = wdx & 7;
    int ks = fp >> 3, n = fp & 7;
    int k = ks * 32 + 8 * (l >> 4) + i;
    int fidx = (n & 3) * 16 + (l & 15);
    float v = 0.f;
    if (fidx < 50) {
      int f = fidx + 1;
      int ph = (f * k) & 255;
      float ang = 0.024543692606170259f * (float)ph; // 2*pi/256
      v = (n >= 4) ? sinf(ang) : cosf(ang);
    }
    ushort hi = f2bf(v);
    ushort lo = f2bf(v - bf2f(hi));
    tabf[(fp * 2 + 0) * 512 + wdx] = hi;
    tabf[(fp * 2 + 1) * 512 + wdx] = lo;
  } else if (bid == 1088) {
    if (tid < 128) {
      int l = tid;
      double cc[3] = {0.0, 0.0, 0.0};
      int j0 = -1;
      for (int t = l * 32; t < l * 32 + 32; t++) {
        double src = ((double)t + 0.5) * (31.0 / 4096.0) - 0.5;
        src = src < 0.0 ? 0.0 : (src > 30.0 ? 30.0 : src);
        int i0 = (int)src;
        if (i0 > 30) i0 = 30;
        int i1 = i0 + 1 > 30 ? 30 : i0 + 1;
        double w = src - (double)i0;
        if (j0 < 0) j0 = i0;
        cc[i0 - j0] += 1.0 - w;
        cc[i1 - j0] += w;
      }
      float4 r;
      r.x = __int_as_float(j0);
      r.y = (float)(cc[0] / 32.0);
      r.z = (float)(cc[1] / 32.0);
      r.w = (float)(cc[2] / 32.0);
      jc[l] = r;
    }
  } else if (bid < 1729) {       // wp1 frags: K=1280, N=128, NT=8
    int e = (bid - 1089) * 256 + tid;
    int fp = e >> 9, wdx = e & 511;
    int l = wdx >> 3, i = wdx & 7;
    int ks = fp >> 3, n = fp & 7;
    int k = ks * 32 + 8 * (l >> 4) + i;
    int col = n * 16 + (l & 15);
    float f = wp1[k * 128 + col];
    ushort hi = f2bf(f);
    ushort lo = f2bf(f - bf2f(hi));
    wp1f[(fp * 2 + 0) * 512 + wdx] = hi;
    wp1f[(fp * 2 + 1) * 512 + wdx] = lo;
  } else if (bid < 1857) {       // wp2 frags: K=128, N=256, NT=16
    int e = (bid - 1729) * 256 + tid;
    int fp = e >> 9, wdx = e & 511;
    int l = wdx >> 3, i = wdx & 7;
    int ks = fp >> 4, n = fp & 15;
    int k = ks * 32 + 8 * (l >> 4) + i;
    int col = n * 16 + (l & 15);
    float f = wp2[k * 256 + col];
    ushort hi = f2bf(f);
    ushort lo = f2bf(f - bf2f(hi));
    wp2f[(fp * 2 + 0) * 512 + wdx] = hi;
    wp2f[(fp * 2 + 1) * 512 + wdx] = lo;
  } else if (bid < 2369) {       // w_fu frags: K=512, N=256, NT=16
    int e = (bid - 1857) * 256 + tid;
    int fp = e >> 9, wdx = e & 511;
    int l = wdx >> 3, i = wdx & 7;
    int ks = fp >> 4, n = fp & 15;
    int k = ks * 32 + 8 * (l >> 4) + i;
    int col = n * 16 + (l & 15);
    float f = w_fu[k * 256 + col];
    ushort hi = f2bf(f);
    ushort lo = f2bf(f - bf2f(hi));
    wfuf[(fp * 2 + 0) * 512 + wdx] = hi;
    wfuf[(fp * 2 + 1) * 512 + wdx] = lo;
  } else {                       // w_out frags: K=256, N=256, NT=16
    int e = (bid - 2369) * 256 + tid;
    int fp = e >> 9, wdx = e & 511;
    int l = wdx >> 3, i = wdx & 7;
    int ks = fp >> 4, n = fp & 15;
    int k = ks * 32 + 8 * (l >> 4) + i;
    int col = n * 16 + (l & 15);
    float f = w_out[k * 256 + col];
    ushort hi = f2bf(f);
    ushort lo = f2bf(f - bf2f(hi));
    woutf[(fp * 2 + 0) * 512 + wdx] = hi;
    woutf[(fp * 2 + 1) * 512 + wdx] = lo;
  }
}

// --------------------------------------------- K2: FUSED 1x1conv+BN1+ReLU -> multi-scale conv
#define XR2 158   // 128 t-tile + 30 halo rows

__device__ __forceinline__ const ushort* afrag_ptr(const ushort* __restrict__ wfb,
                                                   int j, int ks, int h, int l) {
  return wfb + ((((j * 4 + ks) * 2 + h) * 2) << 9) + l * 8;
}

// 32x32x16 conv. Wave owns half h (32 och) x 128 t (4 N-tiles, f32x16 accs).
// Per kk: ALL 8 B-reads issued up-front (fits VGPR budget -> 1 wait), then
// 12 MFMAs round-robin over the 4 independent accumulators (dep distance 4).
// Per-accumulator product order: a_h*bhi, a_h*blo, a_l*bhi (kk=0 then kk=1)
// -> bit-identical to the R1-verified kernel. No setprio.
__device__ __forceinline__ void conv_accum32(
    const ushort* __restrict__ xs, const ushort* __restrict__ wfb,
    int jlo, int jhi, int SH, int h, int l,
    f32x16* __restrict__ acc) {
  int lc = l & 31;
  int lg = l >> 5;
  int U = (jhi - jlo) * 2;   // each u covers one ks-pair {0,1} or {2,3}
#pragma unroll 1
  for (int u = 0; u < U; u++) {
    int j = jlo + (u >> 1);
    int ks0 = (u & 1) * 2;
    const ushort* p0 = afrag_ptr(wfb, j, ks0, h, l);
    const ushort* p1 = afrag_ptr(wfb, j, ks0 + 1, h, l);
    short8 c0h = *(const short8*)p0;
    short8 c0l = *(const short8*)(p0 + 512);
    short8 c1h = *(const short8*)p1;
    short8 c1l = *(const short8*)(p1 + 512);

    int rs = j + SH;
    int base = (lc + rs) * 128;                 // row*128; nt tile = +nt*4096
    int sw = ((lc + rs) & 15) << 3;             // nt*32 rows ≡ 0 mod 16 -> nt-invariant
#pragma unroll
    for (int kk = 0; kk < 2; kk++) {
      int g = (ks0 + kk) * 2 + lg;
      short8 a_h = kk ? c1h : c0h;
      short8 a_l = kk ? c1l : c0l;
      int ohi = (g << 3) ^ sw;
      int olo = ((g + 8) << 3) ^ sw;
      short8 bhi[4], blo[4];
#pragma unroll
      for (int nt = 0; nt < 4; nt++) {
        bhi[nt] = *(const short8*)&xs[base + nt * 4096 + ohi];
        blo[nt] = *(const short8*)&xs[base + nt * 4096 + olo];
      }
#pragma unroll
      for (int nt = 0; nt < 4; nt++)
        acc[nt] = __builtin_amdgcn_mfma_f32_32x32x16_bf16(a_h, bhi[nt], acc[nt], 0, 0, 0);
#pragma unroll
      for (int nt = 0; nt < 4; nt++)
        acc[nt] = __builtin_amdgcn_mfma_f32_32x32x16_bf16(a_h, blo[nt], acc[nt], 0, 0, 0);
#pragma unroll
      for (int nt = 0; nt < 4; nt++)
        acc[nt] = __builtin_amdgcn_mfma_f32_32x32x16_bf16(a_l, bhi[nt], acc[nt], 0, 0, 0);
    }
  }
}

// 32x32 C/D mapping: col(t) = l&31, row(och) = (r&3) + 8*(r>>2) + 4*(l>>5).
__device__ __forceinline__ void conv_epilogue32(
    const f32x16* __restrict__ acc,
    const float* __restrict__ bk, const float* __restrict__ g2,
    const float* __restrict__ be2, const float* __restrict__ m2,
    const float* __restrict__ v2,
    unsigned* __restrict__ y2p, float* __restrict__ pv,
    int b, int t0, int l, int h, int chb) {
  int lc = l & 31, lg = l >> 5;
#pragma unroll
  for (int r = 0; r < 16; r++) {
    int och = chb + h * 32 + (r & 3) + 8 * (r >> 2) + 4 * lg;
    float bias = bk[och - chb];
    float s = g2[och] * rsqrtf(v2[och] + EPS_BN);
    float sh = be2[och] - m2[och] * s;
    long idx = ((long)(b * 256 + och)) * T_LEN + t0 + lc;
    float pl[4];
#pragma unroll
    for (int nt = 0; nt < 4; nt++) {
      float a = acc[nt][r];
      float v = fmaf(fmaxf(a + bias, 0.f), s, sh);
      ushort hi = f2bf(v);
      ushort lo = f2bf(v - bf2f(hi));
      y2p[idx + nt * 32] = (unsigned)hi | ((unsigned)lo << 16);
      pl[nt] = v;
    }
#pragma unroll
    for (int nt = 0; nt < 4; nt++) {
#pragma unroll
      for (int m = 1; m < 32; m <<= 1) pl[nt] += __shfl_xor(pl[nt], m);
    }
    if (lc == 0) {
#pragma unroll
      for (int nt = 0; nt < 4; nt++)
        pv[((long)(b * 128 + (t0 >> 5) + nt)) * 512 + och] = pl[nt] * (1.f / 32.f);
    }
  }
}

__launch_bounds__(512, 4)
__global__ void k2_convbank(const float* __restrict__ x,
    const ushort* __restrict__ wfB,
    const float* __restrict__ b_sp, const float* __restrict__ g1,
    const float* __restrict__ be1, const float* __restrict__ m1,
    const float* __restrict__ v1,
    const ushort* __restrict__ wfrag,
    const float* __restrict__ bt3, const float* __restrict__ bt7,
    const float* __restrict__ bt15, const float* __restrict__ bt31,
    const float* __restrict__ g2, const float* __restrict__ be2,
    const float* __restrict__ m2, const float* __restrict__ v2,
    unsigned* __restrict__ y2p, float* __restrict__ pv) {
  __shared__ __align__(16) ushort xs[XR2 * 128];   // staged tile; reused as f32x4 red[]
  int tid = threadIdx.x;
  int bid = blockIdx.x;
  int b = bid >> 5;
  int t0 = (bid & 31) * 128;
  int l = tid & 63;
  int wid = __builtin_amdgcn_readfirstlane(tid >> 6);
  int lr = l & 15, lg = l >> 4;

  // ---- staging: compute y1 rows into swizzled xs (bit-identical recipe;
  // MFMA order = three n-sweeps, per-acc order preserved).
  // tiles 0..7 -> waves 0..7; extra tiles 8,9 -> lightest conv waves 6,7
  {
    float sbn1[4], cbn1[4];
#pragma unroll
    for (int n = 0; n < 4; n++) {
      int o = n * 16 + lr;
      float s = g1[o] * rsqrtf(v1[o] + EPS_BN);
      sbn1[n] = s;
      cbn1[n] = (b_sp[o] - m1[o]) * s + be1[o];
    }
    const f32x4 z = {0.f, 0.f, 0.f, 0.f};
#pragma unroll 1
    for (int mt = wid; mt < 10; mt += (wid >= 6 ? 2 : 16)) {
      int rowbase = mt * 16;
      long tl = (long)t0 - 15 + rowbase + lr;  // A-load row
      long tc = tl < 0 ? 0 : (tl > T_LEN - 1 ? T_LEN - 1 : tl);
      const float* __restrict__ xp0 = x + ((long)b * T_LEN + tc) * 256 + 8 * lg;
      f32x4 a1x[4];
#pragma unroll
      for (int n = 0; n < 4; n++) a1x[n] = z;
#pragma unroll 2
      for (int s = 0; s < 8; s++) {
        short8 bh[4], bl[4];
#pragma unroll
        for (int n = 0; n < 4; n++) {
          const ushort* bp = wfB + ((s * 4 + n) * 2) * 512 + l * 8;
          bh[n] = *(const short8*)bp;
          bl[n] = *(const short8*)(bp + 512);
        }
        float4 a0 = *(const float4*)(xp0 + s * 32);
        float4 a1 = *(const float4*)(xp0 + s * 32 + 4);
        float av[8] = {a0.x, a0.y, a0.z, a0.w, a1.x, a1.y, a1.z, a1.w};
        short8 ah, al;
#pragma unroll
        for (int i = 0; i < 8; i++) {
          ushort hi = f2bf(av[i]);
          ah[i] = (short)hi;
          al[i] = (short)f2bf(av[i] - bf2f(hi));
        }
#pragma unroll
        for (int n = 0; n < 4; n++)
          a1x[n] = __builtin_amdgcn_mfma_f32_16x16x32_bf16(ah, bh[n], a1x[n], 0, 0, 0);
#pragma unroll
        for (int n = 0; n < 4; n++)
          a1x[n] = __builtin_amdgcn_mfma_f32_16x16x32_bf16(al, bh[n], a1x[n], 0, 0, 0);
#pragma unroll
        for (int n = 0; n < 4; n++)
          a1x[n] = __builtin_amdgcn_mfma_f32_16x16x32_bf16(ah, bl[n], a1x[n], 0, 0, 0);
      }
#pragma unroll
      for (int r = 0; r < 4; r++) {
        int row = rowbase + lg * 4 + r;
        int t = t0 - 15 + row;
        if (row < XR2) {
          int sw = row & 15;
          bool tv = (t >= 0 && t < T_LEN);
#pragma unroll
          for (int n = 0; n < 4; n++) {
            float v = tv ? fmaxf(fmaf(a1x[n][r], sbn1[n], cbn1[n]), 0.f) : 0.f;
            ushort hi = f2bf(v);
            ushort lo = f2bf(v - bf2f(hi));
            int c = n * 16 + lr;
            int g = c >> 3;
            xs[row * 128 + ((g ^ sw) << 3) + (c & 7)] = hi;
            xs[row * 128 + (((g + 8) ^ sw) << 3) + (c & 7)] = lo;
          }
        }
      }
    }
  }
  __syncthreads();

  // ---- conv phase (32x32x16)
  int beta, h, jlo, jhi, role, slot;   // role: 0 direct, 1 flush, 2 add
  switch (wid) {
    case 0:  beta = 3; h = 0; jlo = 0;  jhi = 16; role = 2; slot = 0; break;
    case 1:  beta = 3; h = 0; jlo = 16; jhi = 31; role = 1; slot = 0; break;
    case 2:  beta = 3; h = 1; jlo = 0;  jhi = 16; role = 2; slot = 1; break;
    case 3:  beta = 3; h = 1; jlo = 16; jhi = 31; role = 1; slot = 1; break;
    case 4:  beta = 2; h = 0; jlo = 0;  jhi = 15; role = 0; slot = 0; break;
    case 5:  beta = 2; h = 1; jlo = 0;  jhi = 15; role = 0; slot = 0; break;
    case 6:  beta = 1; h = 0; jlo = 0;  jhi = 7;  role = 0; slot = 0; break;
    default: beta = 1; h = 1; jlo = 0;  jhi = 7;  role = 0; slot = 0; break;
  }
  const int FB[4]  = {0, 48, 160, 400};
  const int SHs[4] = {14, 12, 8, 0};
  const int CHB[4] = {0, 64, 128, 192};
  const float* bk = (beta == 0) ? bt3 : (beta == 1) ? bt7 : (beta == 2) ? bt15 : bt31;

  f32x16 acc[4];
  const f32x16 z16 = {0.f};
#pragma unroll
  for (int nt = 0; nt < 4; nt++) acc[nt] = z16;

  conv_accum32(xs, wfrag + FB[beta] * 512, jlo, jhi, SHs[beta], h, l, acc);
  if (role == 0) {
    conv_epilogue32(acc, bk, g2, be2, m2, v2, y2p, pv, b, t0, l, h, CHB[beta]);
    if (wid >= 6) {   // second pass: K=3 branch on same half
#pragma unroll
      for (int nt = 0; nt < 4; nt++) acc[nt] = z16;
      conv_accum32(xs, wfrag, 0, 3, 14, h, l, acc);
      conv_epilogue32(acc, bt3, g2, be2, m2, v2, y2p, pv, b, t0, l, h, 0);
    }
  }
  __syncthreads();                       // xs reads complete everywhere
  f32x4* red = (f32x4*)xs;
  if (role == 1) {
    f32x4* rp = red + (slot * 64 + l) * 16;
#pragma unroll
    for (int nt = 0; nt < 4; nt++) {
#pragma unroll
      for (int q = 0; q < 4; q++) {
        f32x4 t = {acc[nt][q * 4 + 0], acc[nt][q * 4 + 1],
                   acc[nt][q * 4 + 2], acc[nt][q * 4 + 3]};
        rp[(nt * 4 + q) ^ (l & 15)] = t;
      }
    }
  }
  __syncthreads();
  if (role == 2) {
    const f32x4* rp = red + (slot * 64 + l) * 16;
#pragma unroll
    for (int nt = 0; nt < 4; nt++) {
#pragma unroll
      for (int q = 0; q < 4; q++) {
        f32x4 t = rp[(nt * 4 + q) ^ (l & 15)];
        acc[nt][q * 4 + 0] += t[0];
        acc[nt][q * 4 + 1] += t[1];
        acc[nt][q * 4 + 2] += t[2];
        acc[nt][q * 4 + 3] += t[3];
      }
    }
    conv_epilogue32(acc, bt31, g2, be2, m2, v2, y2p, pv, b, t0, l, h, 192);
  }
}

// --------------------------------------------- K3: windowed DFT powers via MFMA
__launch_bounds__(512)
__global__ void k3_spectral(const unsigned* __restrict__ y2p,
                            const ushort* __restrict__ tabf, float* __restrict__ h0) {
  int tid = threadIdx.x;
  int l = tid & 63;
  int wid = tid >> 6;            // wave owns ch 32*wid .. +31 (2 M-tiles)
  int bid = (int)(blockIdx.x % 8u) * 124 + (int)(blockIdx.x / 8u);
  int win = bid % NWIN;
  int b = bid / NWIN;
  int t0 = win * 128;
  int lr = l & 15, lg = l >> 4;
  f32x4 acc[2][8];
  const f32x4 z = {0.f, 0.f, 0.f, 0.f};
#pragma unroll
  for (int mt = 0; mt < 2; mt++)
#pragma unroll
    for (int n = 0; n < 8; n++) acc[mt][n] = z;
  long abase = ((long)(b * 256 + wid * 32 + lr)) * T_LEN + t0 + 8 * lg;
  const unsigned* __restrict__ xp = y2p + abase;
  uint4 cA0[2], cA1[2];
#pragma unroll
  for (int mt = 0; mt < 2; mt++) {
    const uint4* p = (const uint4*)(xp + (long)mt * 16 * T_LEN);
    cA0[mt] = p[0];
    cA1[mt] = p[1];
  }
#pragma unroll 1
  for (int ks = 0; ks < 8; ks++) {
    uint4 nA0[2], nA1[2];
    if (ks < 7) {
#pragma unroll
      for (int mt = 0; mt < 2; mt++) {
        const uint4* p = (const uint4*)(xp + (long)mt * 16 * T_LEN + (ks + 1) * 32);
        nA0[mt] = p[0];
        nA1[mt] = p[1];
      }
    } else {
#pragma unroll
      for (int mt = 0; mt < 2; mt++) { nA0[mt] = cA0[mt]; nA1[mt] = cA1[mt]; }
    }
    short8 ah[2], al[2];
#pragma unroll
    for (int mt = 0; mt < 2; mt++) {
      unsigned vv[8] = {cA0[mt].x, cA0[mt].y, cA0[mt].z, cA0[mt].w,
                        cA1[mt].x, cA1[mt].y, cA1[mt].z, cA1[mt].w};
#pragma unroll
      for (int i = 0; i < 8; i++) {
        ah[mt][i] = (short)(vv[i] & 0xffffu);
        al[mt][i] = (short)(vv[i] >> 16);
      }
    }
#pragma unroll
    for (int n = 0; n < 8; n++) {
      const ushort* bp = tabf + ((ks * 8 + n) * 2) * 512 + l * 8;
      short8 bh = *(const short8*)bp;
      short8 bl = *(const short8*)(bp + 512);
#pragma unroll
      for (int mt = 0; mt < 2; mt++)
        acc[mt][n] = __builtin_amdgcn_mfma_f32_16x16x32_bf16(ah[mt], bh, acc[mt][n], 0, 0, 0);
#pragma unroll
      for (int mt = 0; mt < 2; mt++)
        acc[mt][n] = __builtin_amdgcn_mfma_f32_16x16x32_bf16(al[mt], bh, acc[mt][n], 0, 0, 0);
#pragma unroll
      for (int mt = 0; mt < 2; mt++)
        acc[mt][n] = __builtin_amdgcn_mfma_f32_16x16x32_bf16(ah[mt], bl, acc[mt][n], 0, 0, 0);
    }
#pragma unroll
    for (int mt = 0; mt < 2; mt++) { cA0[mt] = nA0[mt]; cA1[mt] = nA1[mt]; }
  }
  float wt[4][5];
#pragma unroll
  for (int n = 0; n < 4; n++) {
    int f = n * 16 + lr;
    wt[n][0] = (f <= 3)            ? 0.25f        : 0.f;
    wt[n][1] = (f >= 3 && f <= 7)  ? 0.2f         : 0.f;
    wt[n][2] = (f >= 7 && f <= 12) ? (1.f / 6.f)  : 0.f;
    wt[n][3] = (f >= 12 && f <= 29)? (1.f / 18.f) : 0.f;
    wt[n][4] = (f >= 29 && f <= 49)? (1.f / 21.f) : 0.f;
  }
  long hb = ((long)(b * NWIN + win)) * 1280;
#pragma unroll
  for (int mt = 0; mt < 2; mt++) {
#pragma unroll
    for (int r = 0; r < 4; r++) {
      float p0, p1, p2, p3;
      { float re = acc[mt][0][r], im = acc[mt][4][r]; p0 = re * re + im * im; }
      { float re = acc[mt][1][r], im = acc[mt][5][r]; p1 = re * re + im * im; }
      { float re = acc[mt][2][r], im = acc[mt][6][r]; p2 = re * re + im * im; }
      { float re = acc[mt][3][r], im = acc[mt][7][r]; p3 = re * re + im * im; }
      float s0 = p0 * wt[0][0] + p1 * wt[1][0] + p2 * wt[2][0] + p3 * wt[3][0];
      float s1 = p0 * wt[0][1] + p1 * wt[1][1] + p2 * wt[2][1] + p3 * wt[3][1];
      float s2 = p0 * wt[0][2] + p1 * wt[1][2] + p2 * wt[2][2] + p3 * wt[3][2];
      float s3 = p0 * wt[0][3] + p1 * wt[1][3] + p2 * wt[2][3] + p3 * wt[3][3];
      float s4 = p0 * wt[0][4] + p1 * wt[1][4] + p2 * wt[2][4] + p3 * wt[3][4];
#pragma unroll
      for (int m = 1; m < 16; m <<= 1) {
        s0 += __shfl_xor(s0, m);
        s1 += __shfl_xor(s1, m);
        s2 += __shfl_xor(s2, m);
        s3 += __shfl_xor(s3, m);
        s4 += __shfl_xor(s4, m);
      }
      if (lr < 5) {
        float out = lr == 0 ? s0 : lr == 1 ? s1 : lr == 2 ? s2 : lr == 3 ? s3 : s4;
        int ch = wid * 32 + mt * 16 + lg * 4 + r;
        h0[hb + lr * 256 + ch] = out;
      }
    }
  }
}

// --------------------------------------------- K4: spectral MLP via MFMA
__launch_bounds__(256)
__global__ void k4_mlp(const float* __restrict__ h0, const ushort* __restrict__ wp1f,
                       const float* __restrict__ bp1, const ushort* __restrict__ wp2f,
                       const float* __restrict__ bp2, float* __restrict__ hs) {
  __shared__ ushort t1h[16][136];
  __shared__ ushort t1l[16][136];
  int tid = threadIdx.x;
  int l = tid & 63, wid = tid >> 6;
  int lr = l & 15, lg = l >> 4;
  int r0 = blockIdx.x * 16;
  const float* __restrict__ ap0 = h0 + (long)(r0 + lr) * 1280 + 8 * lg;
  const f32x4 z = {0.f, 0.f, 0.f, 0.f};
  f32x4 acc[2];
  acc[0] = z; acc[1] = z;
#pragma unroll 2
  for (int ks = 0; ks < 40; ks++) {
    float4 a0 = *(const float4*)(ap0 + ks * 32);
    float4 a1 = *(const float4*)(ap0 + ks * 32 + 4);
    float av[8] = {a0.x, a0.y, a0.z, a0.w, a1.x, a1.y, a1.z, a1.w};
    short8 ah, al;
#pragma unroll
    for (int i = 0; i < 8; i++) {
      ushort hi = f2bf(av[i]);
      ah[i] = (short)hi;
      al[i] = (short)f2bf(av[i] - bf2f(hi));
    }
#pragma unroll
    for (int nt = 0; nt < 2; nt++) {
      const ushort* bp = wp1f + ((ks * 8 + wid * 2 + nt) * 2) * 512 + l * 8;
      short8 bh = *(const short8*)bp;
      short8 bl = *(const short8*)(bp + 512);
      acc[nt] = __builtin_amdgcn_mfma_f32_16x16x32_bf16(ah, bh, acc[nt], 0, 0, 0);
      acc[nt] = __builtin_amdgcn_mfma_f32_16x16x32_bf16(al, bh, acc[nt], 0, 0, 0);
      acc[nt] = __builtin_amdgcn_mfma_f32_16x16x32_bf16(ah, bl, acc[nt], 0, 0, 0);
    }
  }
#pragma unroll
  for (int nt = 0; nt < 2; nt++) {
    int col = (wid * 2 + nt) * 16 + lr;
    float bb = bp1[col];
#pragma unroll
    for (int r = 0; r < 4; r++) {
      int row = lg * 4 + r;
      float v = fmaxf(acc[nt][r] + bb, 0.f);
      ushort hi = f2bf(v);
      ushort lo = f2bf(v - bf2f(hi));
      t1h[row][col] = hi;
      t1l[row][col] = lo;
    }
  }
  __syncthreads();
  f32x4 a2[4];
#pragma unroll
  for (int nt = 0; nt < 4; nt++) a2[nt] = z;
#pragma unroll
  for (int ks = 0; ks < 4; ks++) {
    short8 ah = *(const short8*)&t1h[lr][ks * 32 + 8 * lg];
    short8 al = *(const short8*)&t1l[lr][ks * 32 + 8 * lg];
#pragma unroll
    for (int nt = 0; nt < 4; nt++) {
      const ushort* bp = wp2f + ((ks * 16 + wid * 4 + nt) * 2) * 512 + l * 8;
      short8 bh = *(const short8*)bp;
      short8 bl = *(const short8*)(bp + 512);
      a2[nt] = __builtin_amdgcn_mfma_f32_16x16x32_bf16(ah, bh, a2[nt], 0, 0, 0);
      a2[nt] = __builtin_amdgcn_mfma_f32_16x16x32_bf16(al, bh, a2[nt], 0, 0, 0);
      a2[nt] = __builtin_amdgcn_mfma_f32_16x16x32_bf16(ah, bl, a2[nt], 0, 0, 0);
    }
  }
#pragma unroll
  for (int nt = 0; nt < 4; nt++) {
    int col = (wid * 4 + nt) * 16 + lr;
    float bb = bp2[col];
#pragma unroll
    for (int r = 0; r < 4; r++) {
      long row = r0 + lg * 4 + r;
      hs[row * 256 + col] = a2[nt][r] + bb;
    }
  }
}

// --------------------------------------------- K5a: spec interp (3-coef) -> pv
__launch_bounds__(256)
__global__ void k5a_spec(const float* __restrict__ hs, const float4* __restrict__ jc,
                         float* __restrict__ pv) {
  int o = threadIdx.x;
  int l = blockIdx.x & 127, b = blockIdx.x >> 7;
  float4 c = jc[l];
  int j0 = __float_as_int(c.x);
  const float* __restrict__ hb = hs + (long)b * NWIN * 256;
  int i0 = j0 > 30 ? 30 : j0;
  int i1 = j0 + 1 > 30 ? 30 : j0 + 1;
  int i2 = j0 + 2 > 30 ? 30 : j0 + 2;
  float v = c.y * hb[i0 * 256 + o] + c.z * hb[i1 * 256 + o] + c.w * hb[i2 * 256 + o];
  pv[((long)(b * 128 + l)) * 512 + 256 + o] = v;
}

// --------------------------------------------- K5b: fused proj + pos + out proj via MFMA
__launch_bounds__(256)
__global__ void k5b_out(const float* __restrict__ pv, const ushort* __restrict__ wfuf,
                        const float* __restrict__ b_fu, const float* __restrict__ pos,
                        const ushort* __restrict__ woutf, const float* __restrict__ b_out,
                        float* __restrict__ out) {
  __shared__ ushort gh[32][264];
  __shared__ ushort gl[32][264];
  int tid = threadIdx.x;
  int l = tid & 63, wid = tid >> 6;
  int lr = l & 15, lg = l >> 4;
  int mt = wid & 1, nh = wid >> 1;
  int r0 = blockIdx.x * 32;
  int lbase = r0 & 127;
  const float* __restrict__ ap0 = pv + (long)(r0 + mt * 16 + lr) * 512 + 8 * lg;
  const f32x4 z = {0.f, 0.f, 0.f, 0.f};
  f32x4 acc[8];
#pragma unroll
  for (int nt = 0; nt < 8; nt++) acc[nt] = z;
#pragma unroll 1
  for (int ks = 0; ks < 16; ks++) {
    float4 a0 = *(const float4*)(ap0 + ks * 32);
    float4 a1 = *(const float4*)(ap0 + ks * 32 + 4);
    float av[8] = {a0.x, a0.y, a0.z, a0.w, a1.x, a1.y, a1.z, a1.w};
    short8 ah, al;
#pragma unroll
    for (int i = 0; i < 8; i++) {
      ushort hi = f2bf(av[i]);
      ah[i] = (short)hi;
      al[i] = (short)f2bf(av[i] - bf2f(hi));
    }
#pragma unroll
    for (int nt = 0; nt < 8; nt++) {
      const ushort* bp = wfuf + ((ks * 16 + nh * 8 + nt) * 2) * 512 + l * 8;
      short8 bh = *(const short8*)bp;
      short8 bl = *(const short8*)(bp + 512);
      acc[nt] = __builtin_amdgcn_mfma_f32_16x16x32_bf16(ah, bh, acc[nt], 0, 0, 0);
      acc[nt] = __builtin_amdgcn_mfma_f32_16x16x32_bf16(al, bh, acc[nt], 0, 0, 0);
      acc[nt] = __builtin_amdgcn_mfma_f32_16x16x32_bf16(ah, bl, acc[nt], 0, 0, 0);
    }
  }
#pragma unroll
  for (int nt = 0; nt < 8; nt++) {
    int col = (nh * 8 + nt) * 16 + lr;
    float bb = b_fu[col];
#pragma unroll
    for (int r = 0; r < 4; r++) {
      int row = mt * 16 + lg * 4 + r;
      float v = acc[nt][r] + bb + pos[(lbase + row) * 256 + col];
      ushort hi = f2bf(v);
      ushort lo = f2bf(v - bf2f(hi));
      gh[row][col] = hi;
      gl[row][col] = lo;
    }
  }
  __syncthreads();
  f32x4 a2[8];
#pragma unroll
  for (int nt = 0; nt < 8; nt++) a2[nt] = z;
#pragma unroll 1
  for (int ks = 0; ks < 8; ks++) {
    short8 ah = *(const short8*)&gh[mt * 16 + lr][ks * 32 + 8 * lg];
    short8 al = *(const short8*)&gl[mt * 16 + lr][ks * 32 + 8 * lg];
#pragma unroll
    for (int nt = 0; nt < 8; nt++) {
      const ushort* bp = woutf + ((ks * 16 + nh * 8 + nt) * 2) * 512 + l * 8;
      short8 bh = *(const short8*)bp;
      short8 bl = *(const short8*)(bp + 512);
      a2[nt] = __builtin_amdgcn_mfma_f32_16x16x32_bf16(ah, bh, a2[nt], 0, 0, 0);
      a2[nt] = __builtin_amdgcn_mfma_f32_16x16x32_bf16(al, bh, a2[nt], 0, 0, 0);
      a2[nt] = __builtin_amdgcn_mfma_f32_16x16x32_bf16(ah, bl, a2[nt], 0, 0, 0);
    }
  }
#pragma unroll
  for (int nt = 0; nt < 8; nt++) {
    int col = (nh * 8 + nt) * 16 + lr;
    float bb = b_out[col];
#pragma unroll
    for (int r = 0; r < 4; r++) {
      long row = r0 + mt * 16 + lg * 4 + r;
      out[row * 256 + col] = a2[nt][r] + bb;
    }
  }
}

// ---------------------------------------------------------------- launcher
extern "C" void kernel_launch(void* const* d_in, const int* in_sizes, int n_in,
                              void* d_out, int out_size, void* d_ws, size_t ws_size,
                              hipStream_t stream) {
  const float* x    = (const float*)d_in[0];
  const float* w_sp = (const float*)d_in[1];
  const float* b_sp = (const float*)d_in[2];
  const float* g1   = (const float*)d_in[3];
  const float* be1  = (const float*)d_in[4];
  const float* m1   = (const float*)d_in[5];
  const float* v1   = (const float*)d_in[6];
  const float* wt3  = (const float*)d_in[7];
  const float* bt3  = (const float*)d_in[8];
  const float* wt7  = (const float*)d_in[9];
  const float* bt7  = (const float*)d_in[10];
  const float* wt15 = (const float*)d_in[11];
  const float* bt15 = (const float*)d_in[12];
  const float* wt31 = (const float*)d_in[13];
  const float* bt31 = (const float*)d_in[14];
  const float* g2   = (const float*)d_in[15];
  const float* be2  = (const float*)d_in[16];
  const float* m2   = (const float*)d_in[17];
  const float* v2   = (const float*)d_in[18];
  const float* wp1  = (const float*)d_in[19];
  const float* bp1  = (const float*)d_in[20];
  const float* wp2  = (const float*)d_in[21];
  const float* bp2  = (const float*)d_in[22];
  const float* w_fu = (const float*)d_in[23];
  const float* b_fu = (const float*)d_in[24];
  const float* pos  = (const float*)d_in[25];
  const float* w_out= (const float*)d_in[26];
  const float* b_out= (const float*)d_in[27];

  unsigned* y2p = (unsigned*)d_ws;         // 33,554,432 uint (bf16 hi|lo packed)
  float* h0  = (float*)(y2p + 33554432);   //  1,269,760 f32
  float* hs  = h0 + 1269760;               //    253,952
  float* pv  = hs + 253952;                //  2,097,152
  float4* jc = (float4*)(pv + 2097152);    //        128 float4
  ushort* wfrag = (ushort*)(jc + 128);     //    458,752 ushort (conv-bank frags)
  ushort* wfB   = wfrag + 458752;          //     32,768 ushort (1x1 frags)
  ushort* tabf  = wfB + 32768;             //     65,536 ushort (DFT table frags)
  ushort* wp1f  = tabf + 65536;            //    327,680 ushort (wp1 frags)
  ushort* wp2f  = wp1f + 327680;           //     65,536 ushort (wp2 frags)
  ushort* wfuf  = wp2f + 65536;            //    262,144 ushort (w_fu frags)
  ushort* woutf = wfuf + 262144;           //    131,072 ushort (w_out frags)

  k0_all<<<2625, 256, 0, stream>>>(wt3, wt7, wt15, wt31, w_sp, wp1, wp2, w_fu, w_out,
                                   wfrag, wfB, tabf, jc, wp1f, wp2f, wfuf, woutf);
  k2_convbank<<<1024, 512, 0, stream>>>(x, wfB, b_sp, g1, be1, m1, v1,
                                        wfrag, bt3, bt7, bt15, bt31,
                                        g2, be2, m2, v2, y2p, pv);
  k3_spectral<<<32 * NWIN, 512, 0, stream>>>(y2p, tabf, h0);
  k4_mlp<<<62, 256, 0, stream>>>(h0, wp1f, bp1, wp2f, bp2, hs);
  k5a_spec<<<32 * 128, 256, 0, stream>>>(hs, jc, pv);
  k5b_out<<<128, 256, 0, stream>>>(pv, wfuf, b_fu, pos, woutf, b_out,
                                   (float*)d_out);
}

// Round 8
// 367.752 us; speedup vs baseline: 1.2076x; 1.2076x over previous
//
#include <hip/hip_runtime.h>
#include <hip/hip_bf16.h>

#define T_LEN 4096
#define NWIN 31
#define EPS_BN 1e-5f

typedef __attribute__((ext_vector_type(8))) short short8;
typedef __attribute__((ext_vector_type(4))) float f32x4;

__device__ __forceinline__ ushort f2bf(float x) {   // round-to-nearest-even bf16
  unsigned u = __float_as_uint(x);
  return (ushort)((u + 0x7FFFu + ((u >> 16) & 1u)) >> 16);
}
__device__ __forceinline__ float bf2f(ushort h) {
  return __uint_as_float((unsigned)h << 16);
}

// ---------------------------------------------------------------- k0: ALL init
// [0,896) conv-bank frags | [896,960) 1x1 frags | [960,1088) DFT frags |
// 1088 pool coefs | [1089,1729) wp1 frags | [1729,1857) wp2 frags |
// [1857,2369) w_fu frags | [2369,2625) w_out frags
__global__ void k0_all(const float* __restrict__ wt3, const float* __restrict__ wt7,
                       const float* __restrict__ wt15, const float* __restrict__ wt31,
                       const float* __restrict__ w_sp,
                       const float* __restrict__ wp1, const float* __restrict__ wp2,
                       const float* __restrict__ w_fu, const float* __restrict__ w_out,
                       ushort* __restrict__ wfrag, ushort* __restrict__ wfB,
                       ushort* __restrict__ tabf, float4* __restrict__ jc,
                       ushort* __restrict__ wp1f, ushort* __restrict__ wp2f,
                       ushort* __restrict__ wfuf, ushort* __restrict__ woutf) {
  int bid = blockIdx.x;
  int tid = threadIdx.x;
  if (bid < 896) {
    int e = bid * 256 + tid;
    const float* w; int K, base, eb;
    if (e < 12288)       { w = wt3;  K = 3;  base = 0;   eb = e; }
    else if (e < 40960)  { w = wt7;  K = 7;  base = 48;  eb = e - 12288; }
    else if (e < 102400) { w = wt15; K = 15; base = 160; eb = e - 40960; }
    else                 { w = wt31; K = 31; base = 400; eb = e - 102400; }
    int j = eb / 4096;  int v = eb - j * 4096;
    int ks = v >> 11;   int v2 = v & 2047;
    int tile = v2 >> 9; int wdx = v2 & 511;
    int l = wdx >> 3, i = wdx & 7;
    int o = tile * 16 + (l & 15);
    int c = ks * 32 + 8 * (l >> 4) + i;
    float f = w[(o * 64 + c) * K + j];
    ushort hi = f2bf(f);
    ushort lo = f2bf(f - bf2f(hi));
    int fragp = base + ((j * 2 + ks) * 4 + tile) * 2;
    wfrag[fragp * 512 + wdx] = hi;
    wfrag[(fragp + 1) * 512 + wdx] = lo;
  } else if (bid < 960) {
    int e = (bid - 896) * 256 + tid;
    int frag = e >> 9;
    int wdx = e & 511;
    int l = wdx >> 3, i = wdx & 7;
    int s = frag >> 2, n = frag & 3;
    int c = s * 32 + 8 * (l >> 4) + i;
    int o = n * 16 + (l & 15);
    float f = w_sp[o * 256 + c];
    ushort hi = f2bf(f);
    ushort lo = f2bf(f - bf2f(hi));
    wfB[(frag * 2 + 0) * 512 + wdx] = hi;
    wfB[(frag * 2 + 1) * 512 + wdx] = lo;
  } else if (bid < 1088) {
    int e = (bid - 960) * 256 + tid;
    int fp = e >> 9;
    int wdx = e & 511;
    int l = wdx >> 3, i = wdx & 7;
    int ks = fp >> 3, n = fp & 7;
    int k = ks * 32 + 8 * (l >> 4) + i;
    int fidx = (n & 3) * 16 + (l & 15);
    float v = 0.f;
    if (fidx < 50) {
      int f = fidx + 1;
      int ph = (f * k) & 255;
      float ang = 0.024543692606170259f * (float)ph; // 2*pi/256
      v = (n >= 4) ? sinf(ang) : cosf(ang);
    }
    ushort hi = f2bf(v);
    ushort lo = f2bf(v - bf2f(hi));
    tabf[(fp * 2 + 0) * 512 + wdx] = hi;
    tabf[(fp * 2 + 1) * 512 + wdx] = lo;
  } else if (bid == 1088) {
    if (tid < 128) {
      int l = tid;
      double cc[3] = {0.0, 0.0, 0.0};
      int j0 = -1;
      for (int t = l * 32; t < l * 32 + 32; t++) {
        double src = ((double)t + 0.5) * (31.0 / 4096.0) - 0.5;
        src = src < 0.0 ? 0.0 : (src > 30.0 ? 30.0 : src);
        int i0 = (int)src;
        if (i0 > 30) i0 = 30;
        int i1 = i0 + 1 > 30 ? 30 : i0 + 1;
        double w = src - (double)i0;
        if (j0 < 0) j0 = i0;
        cc[i0 - j0] += 1.0 - w;
        cc[i1 - j0] += w;
      }
      float4 r;
      r.x = __int_as_float(j0);
      r.y = (float)(cc[0] / 32.0);
      r.z = (float)(cc[1] / 32.0);
      r.w = (float)(cc[2] / 32.0);
      jc[l] = r;
    }
  } else if (bid < 1729) {       // wp1 frags: K=1280, N=128, NT=8
    int e = (bid - 1089) * 256 + tid;
    int fp = e >> 9, wdx = e & 511;
    int l = wdx >> 3, i = wdx & 7;
    int ks = fp >> 3, n = fp & 7;
    int k = ks * 32 + 8 * (l >> 4) + i;
    int col = n * 16 + (l & 15);
    float f = wp1[k * 128 + col];
    ushort hi = f2bf(f);
    ushort lo = f2bf(f - bf2f(hi));
    wp1f[(fp * 2 + 0) * 512 + wdx] = hi;
    wp1f[(fp * 2 + 1) * 512 + wdx] = lo;
  } else if (bid < 1857) {       // wp2 frags: K=128, N=256, NT=16
    int e = (bid - 1729) * 256 + tid;
    int fp = e >> 9, wdx = e & 511;
    int l = wdx >> 3, i = wdx & 7;
    int ks = fp >> 4, n = fp & 15;
    int k = ks * 32 + 8 * (l >> 4) + i;
    int col = n * 16 + (l & 15);
    float f = wp2[k * 256 + col];
    ushort hi = f2bf(f);
    ushort lo = f2bf(f - bf2f(hi));
    wp2f[(fp * 2 + 0) * 512 + wdx] = hi;
    wp2f[(fp * 2 + 1) * 512 + wdx] = lo;
  } else if (bid < 2369) {       // w_fu frags: K=512, N=256, NT=16
    int e = (bid - 1857) * 256 + tid;
    int fp = e >> 9, wdx = e & 511;
    int l = wdx >> 3, i = wdx & 7;
    int ks = fp >> 4, n = fp & 15;
    int k = ks * 32 + 8 * (l >> 4) + i;
    int col = n * 16 + (l & 15);
    float f = w_fu[k * 256 + col];
    ushort hi = f2bf(f);
    ushort lo = f2bf(f - bf2f(hi));
    wfuf[(fp * 2 + 0) * 512 + wdx] = hi;
    wfuf[(fp * 2 + 1) * 512 + wdx] = lo;
  } else {                       // w_out frags: K=256, N=256, NT=16
    int e = (bid - 2369) * 256 + tid;
    int fp = e >> 9, wdx = e & 511;
    int l = wdx >> 3, i = wdx & 7;
    int ks = fp >> 4, n = fp & 15;
    int k = ks * 32 + 8 * (l >> 4) + i;
    int col = n * 16 + (l & 15);
    float f = w_out[k * 256 + col];
    ushort hi = f2bf(f);
    ushort lo = f2bf(f - bf2f(hi));
    woutf[(fp * 2 + 0) * 512 + wdx] = hi;
    woutf[(fp * 2 + 1) * 512 + wdx] = lo;
  }
}

// --------------------------------------------- K2: FUSED 1x1conv+BN1+ReLU -> multi-scale conv
#define XR2 158   // 128 t-tile + 30 halo rows

// Inner loop: tt-pairs (ta, ta+4), 12 MFMAs round-robin over 4 independent
// accumulators. Per-accumulator order unchanged -> bit-identical. A-frags
// rotated one (j,ks) step ahead.
__device__ __forceinline__ void conv_accum(
    const ushort* __restrict__ xs, const ushort* __restrict__ wfb,
    int jlo, int jhi, int SH, int h, int l,
    f32x4* __restrict__ acc0, f32x4* __restrict__ acc1) {
  int lr = l & 15, lg = l >> 4;
  int U = (jhi - jlo) * 2;   // u enumerates (j,ks) steps
  short8 c0h, c0l, c1h, c1l;
  {
    const ushort* ap = wfb + (((jlo * 2 + 0) * 4 + h * 2) * 2) * 512 + l * 8;
    c0h = *(const short8*)(ap);
    c0l = *(const short8*)(ap + 512);
    c1h = *(const short8*)(ap + 1024);
    c1l = *(const short8*)(ap + 1536);
  }
#pragma unroll 1
  for (int u = 0; u < U; u++) {
    int un = (u + 1 < U) ? u + 1 : u;
    int jn = jlo + (un >> 1), kn = un & 1;
    const ushort* apn = wfb + (((jn * 2 + kn) * 4 + h * 2) * 2) * 512 + l * 8;
    short8 n0h = *(const short8*)(apn);
    short8 n0l = *(const short8*)(apn + 512);
    short8 n1h = *(const short8*)(apn + 1024);
    short8 n1l = *(const short8*)(apn + 1536);

    int j = jlo + (u >> 1), ks = u & 1;
    int rs = j + SH;
    int gb = ks * 4 + lg;
    int sw = ((lr + rs) & 15) << 3;        // tt-invariant (tt*16 ≡ 0 mod 16)
    int ohi = (gb << 3) ^ sw;
    int olo = ((gb + 8) << 3) ^ sw;
    int rb = (lr + rs) * 128;
#pragma unroll
    for (int tp = 0; tp < 4; tp++) {
      int ba = rb + tp * 2048;             // tt = tp
      int bb = rb + tp * 2048 + 8192;      // tt = tp + 4
      short8 bhiA = *(const short8*)&xs[ba + ohi];
      short8 bloA = *(const short8*)&xs[ba + olo];
      short8 bhiB = *(const short8*)&xs[bb + ohi];
      short8 bloB = *(const short8*)&xs[bb + olo];
      acc0[tp]     = __builtin_amdgcn_mfma_f32_16x16x32_bf16(c0h, bhiA, acc0[tp],     0, 0, 0);
      acc1[tp]     = __builtin_amdgcn_mfma_f32_16x16x32_bf16(c1h, bhiA, acc1[tp],     0, 0, 0);
      acc0[tp + 4] = __builtin_amdgcn_mfma_f32_16x16x32_bf16(c0h, bhiB, acc0[tp + 4], 0, 0, 0);
      acc1[tp + 4] = __builtin_amdgcn_mfma_f32_16x16x32_bf16(c1h, bhiB, acc1[tp + 4], 0, 0, 0);
      acc0[tp]     = __builtin_amdgcn_mfma_f32_16x16x32_bf16(c0h, bloA, acc0[tp],     0, 0, 0);
      acc1[tp]     = __builtin_amdgcn_mfma_f32_16x16x32_bf16(c1h, bloA, acc1[tp],     0, 0, 0);
      acc0[tp + 4] = __builtin_amdgcn_mfma_f32_16x16x32_bf16(c0h, bloB, acc0[tp + 4], 0, 0, 0);
      acc1[tp + 4] = __builtin_amdgcn_mfma_f32_16x16x32_bf16(c1h, bloB, acc1[tp + 4], 0, 0, 0);
      acc0[tp]     = __builtin_amdgcn_mfma_f32_16x16x32_bf16(c0l, bhiA, acc0[tp],     0, 0, 0);
      acc1[tp]     = __builtin_amdgcn_mfma_f32_16x16x32_bf16(c1l, bhiA, acc1[tp],     0, 0, 0);
      acc0[tp + 4] = __builtin_amdgcn_mfma_f32_16x16x32_bf16(c0l, bhiB, acc0[tp + 4], 0, 0, 0);
      acc1[tp + 4] = __builtin_amdgcn_mfma_f32_16x16x32_bf16(c1l, bhiB, acc1[tp + 4], 0, 0, 0);
    }
    c0h = n0h; c0l = n0l; c1h = n1h; c1l = n1l;
  }
}

__device__ __forceinline__ void conv_epilogue(
    const f32x4* __restrict__ acc0, const f32x4* __restrict__ acc1,
    const float* __restrict__ bk, const float* __restrict__ g2,
    const float* __restrict__ be2, const float* __restrict__ m2,
    const float* __restrict__ v2,
    unsigned* __restrict__ y2p, float* __restrict__ pv,
    int b, int t0, int l, int h, int chb) {
  int lr = l & 15, lg = l >> 4;
#pragma unroll
  for (int ti = 0; ti < 2; ti++) {
#pragma unroll
    for (int r = 0; r < 4; r++) {
      int och = chb + h * 32 + ti * 16 + 4 * lg + r;
      float bias = bk[och - chb];
      float s = g2[och] * rsqrtf(v2[och] + EPS_BN);
      float sh = be2[och] - m2[och] * s;
      long idx = ((long)(b * 256 + och)) * T_LEN + t0 + lr;
      float pl[4] = {0.f, 0.f, 0.f, 0.f};
#pragma unroll
      for (int tt = 0; tt < 8; tt++) {
        float a = ti ? acc1[tt][r] : acc0[tt][r];
        float v = fmaf(fmaxf(a + bias, 0.f), s, sh);
        ushort hi = f2bf(v);
        ushort lo = f2bf(v - bf2f(hi));
        y2p[idx + tt * 16] = (unsigned)hi | ((unsigned)lo << 16);
        pl[tt >> 1] += v;
      }
#pragma unroll
      for (int j = 0; j < 4; j++) {
#pragma unroll
        for (int m = 1; m < 16; m <<= 1) pl[j] += __shfl_xor(pl[j], m);
      }
      if (lr == 0) {
#pragma unroll
        for (int j = 0; j < 4; j++)
          pv[((long)(b * 128 + (t0 >> 5) + j)) * 512 + och] = pl[j] * (1.f / 32.f);
      }
    }
  }
}

__launch_bounds__(512, 4)
__global__ void k2_convbank(const float* __restrict__ x,
    const ushort* __restrict__ wfB,
    const float* __restrict__ b_sp, const float* __restrict__ g1,
    const float* __restrict__ be1, const float* __restrict__ m1,
    const float* __restrict__ v1,
    const ushort* __restrict__ wfrag,
    const float* __restrict__ bt3, const float* __restrict__ bt7,
    const float* __restrict__ bt15, const float* __restrict__ bt31,
    const float* __restrict__ g2, const float* __restrict__ be2,
    const float* __restrict__ m2, const float* __restrict__ v2,
    unsigned* __restrict__ y2p, float* __restrict__ pv) {
  __shared__ __align__(16) ushort xs[XR2 * 128];   // staged tile; reused as f32x4 red[]
  int tid = threadIdx.x;
  int bid = blockIdx.x;
  int b = bid >> 5;
  int t0 = (bid & 31) * 128;
  int l = tid & 63;
  int wid = __builtin_amdgcn_readfirstlane(tid >> 6);
  int lr = l & 15, lg = l >> 4;

  // ---- staging: compute y1 rows into swizzled xs (bit-identical recipe;
  // MFMA order = three n-sweeps, per-acc order preserved).
  // tiles 0..7 -> waves 0..7; extra tiles 8,9 -> lightest conv waves 6,7
  {
    float sbn1[4], cbn1[4];
#pragma unroll
    for (int n = 0; n < 4; n++) {
      int o = n * 16 + lr;
      float s = g1[o] * rsqrtf(v1[o] + EPS_BN);
      sbn1[n] = s;
      cbn1[n] = (b_sp[o] - m1[o]) * s + be1[o];
    }
    const f32x4 z = {0.f, 0.f, 0.f, 0.f};
#pragma unroll 1
    for (int mt = wid; mt < 10; mt += (wid >= 6 ? 2 : 16)) {
      int rowbase = mt * 16;
      long tl = (long)t0 - 15 + rowbase + lr;  // A-load row
      long tc = tl < 0 ? 0 : (tl > T_LEN - 1 ? T_LEN - 1 : tl);
      const float* __restrict__ xp0 = x + ((long)b * T_LEN + tc) * 256 + 8 * lg;
      f32x4 a1x[4];
#pragma unroll
      for (int n = 0; n < 4; n++) a1x[n] = z;
#pragma unroll 2
      for (int s = 0; s < 8; s++) {
        short8 bh[4], bl[4];
#pragma unroll
        for (int n = 0; n < 4; n++) {
          const ushort* bp = wfB + ((s * 4 + n) * 2) * 512 + l * 8;
          bh[n] = *(const short8*)bp;
          bl[n] = *(const short8*)(bp + 512);
        }
        float4 a0 = *(const float4*)(xp0 + s * 32);
        float4 a1 = *(const float4*)(xp0 + s * 32 + 4);
        float av[8] = {a0.x, a0.y, a0.z, a0.w, a1.x, a1.y, a1.z, a1.w};
        short8 ah, al;
#pragma unroll
        for (int i = 0; i < 8; i++) {
          ushort hi = f2bf(av[i]);
          ah[i] = (short)hi;
          al[i] = (short)f2bf(av[i] - bf2f(hi));
        }
#pragma unroll
        for (int n = 0; n < 4; n++)
          a1x[n] = __builtin_amdgcn_mfma_f32_16x16x32_bf16(ah, bh[n], a1x[n], 0, 0, 0);
#pragma unroll
        for (int n = 0; n < 4; n++)
          a1x[n] = __builtin_amdgcn_mfma_f32_16x16x32_bf16(al, bh[n], a1x[n], 0, 0, 0);
#pragma unroll
        for (int n = 0; n < 4; n++)
          a1x[n] = __builtin_amdgcn_mfma_f32_16x16x32_bf16(ah, bl[n], a1x[n], 0, 0, 0);
      }
#pragma unroll
      for (int r = 0; r < 4; r++) {
        int row = rowbase + lg * 4 + r;
        int t = t0 - 15 + row;
        if (row < XR2) {
          int sw = row & 15;
          bool tv = (t >= 0 && t < T_LEN);
#pragma unroll
          for (int n = 0; n < 4; n++) {
            float v = tv ? fmaxf(fmaf(a1x[n][r], sbn1[n], cbn1[n]), 0.f) : 0.f;
            ushort hi = f2bf(v);
            ushort lo = f2bf(v - bf2f(hi));
            int c = n * 16 + lr;
            int g = c >> 3;
            xs[row * 128 + ((g ^ sw) << 3) + (c & 7)] = hi;
            xs[row * 128 + (((g + 8) ^ sw) << 3) + (c & 7)] = lo;
          }
        }
      }
    }
  }
  __syncthreads();

  // ---- conv phase
  int beta, h, jlo, jhi, role, slot;   // role: 0 direct, 1 flush, 2 add
  switch (wid) {
    case 0:  beta = 3; h = 0; jlo = 0;  jhi = 16; role = 2; slot = 0; break;
    case 1:  beta = 3; h = 0; jlo = 16; jhi = 31; role = 1; slot = 0; break;
    case 2:  beta = 3; h = 1; jlo = 0;  jhi = 16; role = 2; slot = 1; break;
    case 3:  beta = 3; h = 1; jlo = 16; jhi = 31; role = 1; slot = 1; break;
    case 4:  beta = 2; h = 0; jlo = 0;  jhi = 15; role = 0; slot = 0; break;
    case 5:  beta = 2; h = 1; jlo = 0;  jhi = 15; role = 0; slot = 0; break;
    case 6:  beta = 1; h = 0; jlo = 0;  jhi = 7;  role = 0; slot = 0; break;
    default: beta = 1; h = 1; jlo = 0;  jhi = 7;  role = 0; slot = 0; break;
  }
  const int FB[4]  = {0, 48, 160, 400};
  const int SHs[4] = {14, 12, 8, 0};
  const int CHB[4] = {0, 64, 128, 192};
  const float* bk = (beta == 0) ? bt3 : (beta == 1) ? bt7 : (beta == 2) ? bt15 : bt31;

  f32x4 acc0[8], acc1[8];
  const f32x4 z = {0.f, 0.f, 0.f, 0.f};
#pragma unroll
  for (int tt = 0; tt < 8; tt++) { acc0[tt] = z; acc1[tt] = z; }

  conv_accum(xs, wfrag + FB[beta] * 512, jlo, jhi, SHs[beta], h, l, acc0, acc1);
  if (role == 0) {
    conv_epilogue(acc0, acc1, bk, g2, be2, m2, v2, y2p, pv, b, t0, l, h, CHB[beta]);
    if (wid >= 6) {   // second pass: K=3 branch on same half
#pragma unroll
      for (int tt = 0; tt < 8; tt++) { acc0[tt] = z; acc1[tt] = z; }
      conv_accum(xs, wfrag, 0, 3, 14, h, l, acc0, acc1);
      conv_epilogue(acc0, acc1, bt3, g2, be2, m2, v2, y2p, pv, b, t0, l, h, 0);
    }
  }
  __syncthreads();                       // xs reads complete everywhere
  f32x4* red = (f32x4*)xs;
  if (role == 1) {
    f32x4* rp = red + (slot * 64 + l) * 16;
#pragma unroll
    for (int tt = 0; tt < 8; tt++) {
      rp[(tt * 2 + 0) ^ (l & 15)] = acc0[tt];
      rp[(tt * 2 + 1) ^ (l & 15)] = acc1[tt];
    }
  }
  __syncthreads();
  if (role == 2) {
    const f32x4* rp = red + (slot * 64 + l) * 16;
#pragma unroll
    for (int tt = 0; tt < 8; tt++) {
      acc0[tt] += rp[(tt * 2 + 0) ^ (l & 15)];
      acc1[tt] += rp[(tt * 2 + 1) ^ (l & 15)];
    }
    conv_epilogue(acc0, acc1, bt31, g2, be2, m2, v2, y2p, pv, b, t0, l, h, 192);
  }
}

// --------------------------------------------- K3: windowed DFT powers via MFMA
__launch_bounds__(512)
__global__ void k3_spectral(const unsigned* __restrict__ y2p,
                            const ushort* __restrict__ tabf, float* __restrict__ h0) {
  int tid = threadIdx.x;
  int l = tid & 63;
  int wid = tid >> 6;            // wave owns ch 32*wid .. +31 (2 M-tiles)
  int bid = (int)(blockIdx.x % 8u) * 124 + (int)(blockIdx.x / 8u);
  int win = bid % NWIN;
  int b = bid / NWIN;
  int t0 = win * 128;
  int lr = l & 15, lg = l >> 4;
  f32x4 acc[2][8];
  const f32x4 z = {0.f, 0.f, 0.f, 0.f};
#pragma unroll
  for (int mt = 0; mt < 2; mt++)
#pragma unroll
    for (int n = 0; n < 8; n++) acc[mt][n] = z;
  long abase = ((long)(b * 256 + wid * 32 + lr)) * T_LEN + t0 + 8 * lg;
  const unsigned* __restrict__ xp = y2p + abase;
  uint4 cA0[2], cA1[2];
#pragma unroll
  for (int mt = 0; mt < 2; mt++) {
    const uint4* p = (const uint4*)(xp + (long)mt * 16 * T_LEN);
    cA0[mt] = p[0];
    cA1[mt] = p[1];
  }
#pragma unroll 1
  for (int ks = 0; ks < 8; ks++) {
    uint4 nA0[2], nA1[2];
    if (ks < 7) {
#pragma unroll
      for (int mt = 0; mt < 2; mt++) {
        const uint4* p = (const uint4*)(xp + (long)mt * 16 * T_LEN + (ks + 1) * 32);
        nA0[mt] = p[0];
        nA1[mt] = p[1];
      }
    } else {
#pragma unroll
      for (int mt = 0; mt < 2; mt++) { nA0[mt] = cA0[mt]; nA1[mt] = cA1[mt]; }
    }
    short8 ah[2], al[2];
#pragma unroll
    for (int mt = 0; mt < 2; mt++) {
      unsigned vv[8] = {cA0[mt].x, cA0[mt].y, cA0[mt].z, cA0[mt].w,
                        cA1[mt].x, cA1[mt].y, cA1[mt].z, cA1[mt].w};
#pragma unroll
      for (int i = 0; i < 8; i++) {
        ah[mt][i] = (short)(vv[i] & 0xffffu);
        al[mt][i] = (short)(vv[i] >> 16);
      }
    }
#pragma unroll
    for (int n = 0; n < 8; n++) {
      const ushort* bp = tabf + ((ks * 8 + n) * 2) * 512 + l * 8;
      short8 bh = *(const short8*)bp;
      short8 bl = *(const short8*)(bp + 512);
#pragma unroll
      for (int mt = 0; mt < 2; mt++)
        acc[mt][n] = __builtin_amdgcn_mfma_f32_16x16x32_bf16(ah[mt], bh, acc[mt][n], 0, 0, 0);
#pragma unroll
      for (int mt = 0; mt < 2; mt++)
        acc[mt][n] = __builtin_amdgcn_mfma_f32_16x16x32_bf16(al[mt], bh, acc[mt][n], 0, 0, 0);
#pragma unroll
      for (int mt = 0; mt < 2; mt++)
        acc[mt][n] = __builtin_amdgcn_mfma_f32_16x16x32_bf16(ah[mt], bl, acc[mt][n], 0, 0, 0);
    }
#pragma unroll
    for (int mt = 0; mt < 2; mt++) { cA0[mt] = nA0[mt]; cA1[mt] = nA1[mt]; }
  }
  float wt[4][5];
#pragma unroll
  for (int n = 0; n < 4; n++) {
    int f = n * 16 + lr;
    wt[n][0] = (f <= 3)            ? 0.25f        : 0.f;
    wt[n][1] = (f >= 3 && f <= 7)  ? 0.2f         : 0.f;
    wt[n][2] = (f >= 7 && f <= 12) ? (1.f / 6.f)  : 0.f;
    wt[n][3] = (f >= 12 && f <= 29)? (1.f / 18.f) : 0.f;
    wt[n][4] = (f >= 29 && f <= 49)? (1.f / 21.f) : 0.f;
  }
  long hb = ((long)(b * NWIN + win)) * 1280;
#pragma unroll
  for (int mt = 0; mt < 2; mt++) {
#pragma unroll
    for (int r = 0; r < 4; r++) {
      float p0, p1, p2, p3;
      { float re = acc[mt][0][r], im = acc[mt][4][r]; p0 = re * re + im * im; }
      { float re = acc[mt][1][r], im = acc[mt][5][r]; p1 = re * re + im * im; }
      { float re = acc[mt][2][r], im = acc[mt][6][r]; p2 = re * re + im * im; }
      { float re = acc[mt][3][r], im = acc[mt][7][r]; p3 = re * re + im * im; }
      float s0 = p0 * wt[0][0] + p1 * wt[1][0] + p2 * wt[2][0] + p3 * wt[3][0];
      float s1 = p0 * wt[0][1] + p1 * wt[1][1] + p2 * wt[2][1] + p3 * wt[3][1];
      float s2 = p0 * wt[0][2] + p1 * wt[1][2] + p2 * wt[2][2] + p3 * wt[3][2];
      float s3 = p0 * wt[0][3] + p1 * wt[1][3] + p2 * wt[2][3] + p3 * wt[3][3];
      float s4 = p0 * wt[0][4] + p1 * wt[1][4] + p2 * wt[2][4] + p3 * wt[3][4];
#pragma unroll
      for (int m = 1; m < 16; m <<= 1) {
        s0 += __shfl_xor(s0, m);
        s1 += __shfl_xor(s1, m);
        s2 += __shfl_xor(s2, m);
        s3 += __shfl_xor(s3, m);
        s4 += __shfl_xor(s4, m);
      }
      if (lr < 5) {
        float out = lr == 0 ? s0 : lr == 1 ? s1 : lr == 2 ? s2 : lr == 3 ? s3 : s4;
        int ch = wid * 32 + mt * 16 + lg * 4 + r;
        h0[hb + lr * 256 + ch] = out;
      }
    }
  }
}

// --------------------------------------------- K4: spectral MLP via MFMA
__launch_bounds__(256)
__global__ void k4_mlp(const float* __restrict__ h0, const ushort* __restrict__ wp1f,
                       const float* __restrict__ bp1, const ushort* __restrict__ wp2f,
                       const float* __restrict__ bp2, float* __restrict__ hs) {
  __shared__ ushort t1h[16][136];
  __shared__ ushort t1l[16][136];
  int tid = threadIdx.x;
  int l = tid & 63, wid = tid >> 6;
  int lr = l & 15, lg = l >> 4;
  int r0 = blockIdx.x * 16;
  const float* __restrict__ ap0 = h0 + (long)(r0 + lr) * 1280 + 8 * lg;
  const f32x4 z = {0.f, 0.f, 0.f, 0.f};
  f32x4 acc[2];
  acc[0] = z; acc[1] = z;
#pragma unroll 2
  for (int ks = 0; ks < 40; ks++) {
    float4 a0 = *(const float4*)(ap0 + ks * 32);
    float4 a1 = *(const float4*)(ap0 + ks * 32 + 4);
    float av[8] = {a0.x, a0.y, a0.z, a0.w, a1.x, a1.y, a1.z, a1.w};
    short8 ah, al;
#pragma unroll
    for (int i = 0; i < 8; i++) {
      ushort hi = f2bf(av[i]);
      ah[i] = (short)hi;
      al[i] = (short)f2bf(av[i] - bf2f(hi));
    }
#pragma unroll
    for (int nt = 0; nt < 2; nt++) {
      const ushort* bp = wp1f + ((ks * 8 + wid * 2 + nt) * 2) * 512 + l * 8;
      short8 bh = *(const short8*)bp;
      short8 bl = *(const short8*)(bp + 512);
      acc[nt] = __builtin_amdgcn_mfma_f32_16x16x32_bf16(ah, bh, acc[nt], 0, 0, 0);
      acc[nt] = __builtin_amdgcn_mfma_f32_16x16x32_bf16(al, bh, acc[nt], 0, 0, 0);
      acc[nt] = __builtin_amdgcn_mfma_f32_16x16x32_bf16(ah, bl, acc[nt], 0, 0, 0);
    }
  }
#pragma unroll
  for (int nt = 0; nt < 2; nt++) {
    int col = (wid * 2 + nt) * 16 + lr;
    float bb = bp1[col];
#pragma unroll
    for (int r = 0; r < 4; r++) {
      int row = lg * 4 + r;
      float v = fmaxf(acc[nt][r] + bb, 0.f);
      ushort hi = f2bf(v);
      ushort lo = f2bf(v - bf2f(hi));
      t1h[row][col] = hi;
      t1l[row][col] = lo;
    }
  }
  __syncthreads();
  f32x4 a2[4];
#pragma unroll
  for (int nt = 0; nt < 4; nt++) a2[nt] = z;
#pragma unroll
  for (int ks = 0; ks < 4; ks++) {
    short8 ah = *(const short8*)&t1h[lr][ks * 32 + 8 * lg];
    short8 al = *(const short8*)&t1l[lr][ks * 32 + 8 * lg];
#pragma unroll
    for (int nt = 0; nt < 4; nt++) {
      const ushort* bp = wp2f + ((ks * 16 + wid * 4 + nt) * 2) * 512 + l * 8;
      short8 bh = *(const short8*)bp;
      short8 bl = *(const short8*)(bp + 512);
      a2[nt] = __builtin_amdgcn_mfma_f32_16x16x32_bf16(ah, bh, a2[nt], 0, 0, 0);
      a2[nt] = __builtin_amdgcn_mfma_f32_16x16x32_bf16(al, bh, a2[nt], 0, 0, 0);
      a2[nt] = __builtin_amdgcn_mfma_f32_16x16x32_bf16(ah, bl, a2[nt], 0, 0, 0);
    }
  }
#pragma unroll
  for (int nt = 0; nt < 4; nt++) {
    int col = (wid * 4 + nt) * 16 + lr;
    float bb = bp2[col];
#pragma unroll
    for (int r = 0; r < 4; r++) {
      long row = r0 + lg * 4 + r;
      hs[row * 256 + col] = a2[nt][r] + bb;
    }
  }
}

// --------------------------------------------- K5a: spec interp (3-coef) -> pv
__launch_bounds__(256)
__global__ void k5a_spec(const float* __restrict__ hs, const float4* __restrict__ jc,
                         float* __restrict__ pv) {
  int o = threadIdx.x;
  int l = blockIdx.x & 127, b = blockIdx.x >> 7;
  float4 c = jc[l];
  int j0 = __float_as_int(c.x);
  const float* __restrict__ hb = hs + (long)b * NWIN * 256;
  int i0 = j0 > 30 ? 30 : j0;
  int i1 = j0 + 1 > 30 ? 30 : j0 + 1;
  int i2 = j0 + 2 > 30 ? 30 : j0 + 2;
  float v = c.y * hb[i0 * 256 + o] + c.z * hb[i1 * 256 + o] + c.w * hb[i2 * 256 + o];
  pv[((long)(b * 128 + l)) * 512 + 256 + o] = v;
}

// --------------------------------------------- K5b: fused proj + pos + out proj via MFMA
__launch_bounds__(256)
__global__ void k5b_out(const float* __restrict__ pv, const ushort* __restrict__ wfuf,
                        const float* __restrict__ b_fu, const float* __restrict__ pos,
                        const ushort* __restrict__ woutf, const float* __restrict__ b_out,
                        float* __restrict__ out) {
  __shared__ ushort gh[32][264];
  __shared__ ushort gl[32][264];
  int tid = threadIdx.x;
  int l = tid & 63, wid = tid >> 6;
  int lr = l & 15, lg = l >> 4;
  int mt = wid & 1, nh = wid >> 1;
  int r0 = blockIdx.x * 32;
  int lbase = r0 & 127;
  const float* __restrict__ ap0 = pv + (long)(r0 + mt * 16 + lr) * 512 + 8 * lg;
  const f32x4 z = {0.f, 0.f, 0.f, 0.f};
  f32x4 acc[8];
#pragma unroll
  for (int nt = 0; nt < 8; nt++) acc[nt] = z;
#pragma unroll 1
  for (int ks = 0; ks < 16; ks++) {
    float4 a0 = *(const float4*)(ap0 + ks * 32);
    float4 a1 = *(const float4*)(ap0 + ks * 32 + 4);
    float av[8] = {a0.x, a0.y, a0.z, a0.w, a1.x, a1.y, a1.z, a1.w};
    short8 ah, al;
#pragma unroll
    for (int i = 0; i < 8; i++) {
      ushort hi = f2bf(av[i]);
      ah[i] = (short)hi;
      al[i] = (short)f2bf(av[i] - bf2f(hi));
    }
#pragma unroll
    for (int nt = 0; nt < 8; nt++) {
      const ushort* bp = wfuf + ((ks * 16 + nh * 8 + nt) * 2) * 512 + l * 8;
      short8 bh = *(const short8*)bp;
      short8 bl = *(const short8*)(bp + 512);
      acc[nt] = __builtin_amdgcn_mfma_f32_16x16x32_bf16(ah, bh, acc[nt], 0, 0, 0);
      acc[nt] = __builtin_amdgcn_mfma_f32_16x16x32_bf16(al, bh, acc[nt], 0, 0, 0);
      acc[nt] = __builtin_amdgcn_mfma_f32_16x16x32_bf16(ah, bl, acc[nt], 0, 0, 0);
    }
  }
#pragma unroll
  for (int nt = 0; nt < 8; nt++) {
    int col = (nh * 8 + nt) * 16 + lr;
    float bb = b_fu[col];
#pragma unroll
    for (int r = 0; r < 4; r++) {
      int row = mt * 16 + lg * 4 + r;
      float v = acc[nt][r] + bb + pos[(lbase + row) * 256 + col];
      ushort hi = f2bf(v);
      ushort lo = f2bf(v - bf2f(hi));
      gh[row][col] = hi;
      gl[row][col] = lo;
    }
  }
  __syncthreads();
  f32x4 a2[8];
#pragma unroll
  for (int nt = 0; nt < 8; nt++) a2[nt] = z;
#pragma unroll 1
  for (int ks = 0; ks < 8; ks++) {
    short8 ah = *(const short8*)&gh[mt * 16 + lr][ks * 32 + 8 * lg];
    short8 al = *(const short8*)&gl[mt * 16 + lr][ks * 32 + 8 * lg];
#pragma unroll
    for (int nt = 0; nt < 8; nt++) {
      const ushort* bp = woutf + ((ks * 16 + nh * 8 + nt) * 2) * 512 + l * 8;
      short8 bh = *(const short8*)bp;
      short8 bl = *(const short8*)(bp + 512);
      a2[nt] = __builtin_amdgcn_mfma_f32_16x16x32_bf16(ah, bh, a2[nt], 0, 0, 0);
      a2[nt] = __builtin_amdgcn_mfma_f32_16x16x32_bf16(al, bh, a2[nt], 0, 0, 0);
      a2[nt] = __builtin_amdgcn_mfma_f32_16x16x32_bf16(ah, bl, a2[nt], 0, 0, 0);
    }
  }
#pragma unroll
  for (int nt = 0; nt < 8; nt++) {
    int col = (nh * 8 + nt) * 16 + lr;
    float bb = b_out[col];
#pragma unroll
    for (int r = 0; r < 4; r++) {
      long row = r0 + mt * 16 + lg * 4 + r;
      out[row * 256 + col] = a2[nt][r] + bb;
    }
  }
}

// ---------------------------------------------------------------- launcher
extern "C" void kernel_launch(void* const* d_in, const int* in_sizes, int n_in,
                              void* d_out, int out_size, void* d_ws, size_t ws_size,
                              hipStream_t stream) {
  const float* x    = (const float*)d_in[0];
  const float* w_sp = (const float*)d_in[1];
  const float* b_sp = (const float*)d_in[2];
  const float* g1   = (const float*)d_in[3];
  const float* be1  = (const float*)d_in[4];
  const float* m1   = (const float*)d_in[5];
  const float* v1   = (const float*)d_in[6];
  const float* wt3  = (const float*)d_in[7];
  const float* bt3  = (const float*)d_in[8];
  const float* wt7  = (const float*)d_in[9];
  const float* bt7  = (const float*)d_in[10];
  const float* wt15 = (const float*)d_in[11];
  const float* bt15 = (const float*)d_in[12];
  const float* wt31 = (const float*)d_in[13];
  const float* bt31 = (const float*)d_in[14];
  const float* g2   = (const float*)d_in[15];
  const float* be2  = (const float*)d_in[16];
  const float* m2   = (const float*)d_in[17];
  const float* v2   = (const float*)d_in[18];
  const float* wp1  = (const float*)d_in[19];
  const float* bp1  = (const float*)d_in[20];
  const float* wp2  = (const float*)d_in[21];
  const float* bp2  = (const float*)d_in[22];
  const float* w_fu = (const float*)d_in[23];
  const float* b_fu = (const float*)d_in[24];
  const float* pos  = (const float*)d_in[25];
  const float* w_out= (const float*)d_in[26];
  const float* b_out= (const float*)d_in[27];

  unsigned* y2p = (unsigned*)d_ws;         // 33,554,432 uint (bf16 hi|lo packed)
  float* h0  = (float*)(y2p + 33554432);   //  1,269,760 f32
  float* hs  = h0 + 1269760;               //    253,952
  float* pv  = hs + 253952;                //  2,097,152
  float4* jc = (float4*)(pv + 2097152);    //        128 float4
  ushort* wfrag = (ushort*)(jc + 128);     //    458,752 ushort (conv-bank frags)
  ushort* wfB   = wfrag + 458752;          //     32,768 ushort (1x1 frags)
  ushort* tabf  = wfB + 32768;             //     65,536 ushort (DFT table frags)
  ushort* wp1f  = tabf + 65536;            //    327,680 ushort (wp1 frags)
  ushort* wp2f  = wp1f + 327680;           //     65,536 ushort (wp2 frags)
  ushort* wfuf  = wp2f + 65536;            //    262,144 ushort (w_fu frags)
  ushort* woutf = wfuf + 262144;           //    131,072 ushort (w_out frags)

  k0_all<<<2625, 256, 0, stream>>>(wt3, wt7, wt15, wt31, w_sp, wp1, wp2, w_fu, w_out,
                                   wfrag, wfB, tabf, jc, wp1f, wp2f, wfuf, woutf);
  k2_convbank<<<1024, 512, 0, stream>>>(x, wfB, b_sp, g1, be1, m1, v1,
                                        wfrag, bt3, bt7, bt15, bt31,
                                        g2, be2, m2, v2, y2p, pv);
  k3_spectral<<<32 * NWIN, 512, 0, stream>>>(y2p, tabf, h0);
  k4_mlp<<<62, 256, 0, stream>>>(h0, wp1f, bp1, wp2f, bp2, hs);
  k5a_spec<<<32 * 128, 256, 0, stream>>>(hs, jc, pv);
  k5b_out<<<128, 256, 0, stream>>>(pv, wfuf, b_fu, pos, woutf, b_out,
                                   (float*)d_out);
}